// Round 9
// baseline (151.626 us; speedup 1.0000x reference)
//
#include <hip/hip_runtime.h>
#include <math.h>

#define C 128
#define N 4096
#define B 2
#define CPG 32

typedef __attribute__((ext_vector_type(8))) short bf16x8;
typedef __attribute__((ext_vector_type(4))) float f32x4;

static __device__ __forceinline__ ushort f2bf(float f) {
  unsigned u = __float_as_uint(f);
  unsigned r = (u + 0x7fffu + ((u >> 16) & 1u)) >> 16;  // RNE
  return (ushort)r;
}

// ---------------------------------------------------------------------------
// Kernel 1: GroupNorm per-slice sums (y=0,1) + weight fp32->bf16 (y=2, x<32).
// stats[t][bg][slice][2] — each slot written by exactly one block: no atomics.
// ---------------------------------------------------------------------------
__global__ __launch_bounds__(256) void gn_partial_kernel(
    const float* __restrict__ x, const float* __restrict__ cc,
    const float* __restrict__ wq, const float* __restrict__ wk,
    const float* __restrict__ wv, const float* __restrict__ wp,
    float* __restrict__ stats, ushort* __restrict__ wb) {
  if (blockIdx.y == 2) {
    if (blockIdx.x >= 32) return;
    int idx = (blockIdx.x * 256 + threadIdx.x) * 8;   // [0, 65536)
    const float* srcs[4] = {wq, wk, wv, wp};
    const float* s = srcs[idx >> 14] + (idx & 16383);
    float4 a = *(const float4*)s;
    float4 b2 = *(const float4*)(s + 4);
    ushort h[8];
    h[0] = f2bf(a.x);  h[1] = f2bf(a.y);  h[2] = f2bf(a.z);  h[3] = f2bf(a.w);
    h[4] = f2bf(b2.x); h[5] = f2bf(b2.y); h[6] = f2bf(b2.z); h[7] = f2bf(b2.w);
    *(uint4*)(wb + idx) = *(uint4*)h;
    return;
  }
  const int t = blockIdx.y;
  const int bg = blockIdx.x >> 3, slice = blockIdx.x & 7;
  const float* in = (t == 0) ? x : cc;
  const float4* base = (const float4*)(in + (size_t)bg * CPG * N + slice * 16384);
  float s = 0.f, sq = 0.f;
  #pragma unroll
  for (int k = 0; k < 16; ++k) {
    float4 v = base[threadIdx.x + k * 256];
    s  += v.x + v.y + v.z + v.w;
    sq += v.x * v.x + v.y * v.y + v.z * v.z + v.w * v.w;
  }
  #pragma unroll
  for (int off = 32; off > 0; off >>= 1) {
    s  += __shfl_down(s, off, 64);
    sq += __shfl_down(sq, off, 64);
  }
  __shared__ float ss[4], ssq[4];
  const int wid = threadIdx.x >> 6;
  if ((threadIdx.x & 63) == 0) { ss[wid] = s; ssq[wid] = sq; }
  __syncthreads();
  if (threadIdx.x == 0) {
    stats[((t * 8 + bg) * 8 + slice) * 2 + 0] = ss[0] + ss[1] + ss[2] + ss[3];
    stats[((t * 8 + bg) * 8 + slice) * 2 + 1] = ssq[0] + ssq[1] + ssq[2] + ssq[3];
  }
}

// ---------------------------------------------------------------------------
// Kernel 2: MFMA qkv. grid=(128 i-tiles of 32, 2 b, 2 z). z=0: q from cc.
// z=1: k AND v from x (one staging serves both GEMMs).
// ---------------------------------------------------------------------------
__global__ __launch_bounds__(256) void qkv_kernel(
    const float* __restrict__ x, const float* __restrict__ cc,
    const float* __restrict__ g1, const float* __restrict__ b1,
    const float* __restrict__ g2, const float* __restrict__ b2,
    const ushort* __restrict__ wqb, const ushort* __restrict__ wkb,
    const ushort* __restrict__ wvb,
    const float* __restrict__ bq, const float* __restrict__ bk,
    const float* __restrict__ bv, const float* __restrict__ stats,
    ushort* __restrict__ qt, ushort* __restrict__ kt, ushort* __restrict__ vb) {
  const int z     = blockIdx.z;           // 0: q(cc), 1: k+v(x)
  const int b     = blockIdx.y;
  const int i0    = blockIdx.x * 32;
  const int tid   = threadIdx.x;
  const int nm    = z ? 2 : 1;

  const float* in    = z ? x : cc;
  const float* gamma = z ? g1 : g2;
  const float* beta  = z ? b1 : b2;
  const int tensor   = z ? 0 : 1;

  __shared__ float a_s[C], d_s[C];
  __shared__ __align__(16) ushort xt[32 * 136];  // Xn^T [i][c]
  if (tid < C) {
    const int ch = tid, g = ch >> 5;
    const float cnt = (float)(CPG * N);
    float S = 0.f, SQ = 0.f;
    #pragma unroll
    for (int sl = 0; sl < 8; ++sl) {
      S  += stats[((tensor * 8 + b * 4 + g) * 8 + sl) * 2 + 0];
      SQ += stats[((tensor * 8 + b * 4 + g) * 8 + sl) * 2 + 1];
    }
    float mean = S / cnt;
    float var  = SQ / cnt - mean * mean;
    float rstd = rsqrtf(var + 1e-6f);
    float ga = gamma[ch];
    a_s[ch] = rstd * ga;
    d_s[ch] = beta[ch] - mean * rstd * ga;
  }
  __syncthreads();

  {  // stage + normalize + transpose: thread covers (c = tid>>1, 16 i's)
    const int c = tid >> 1, ih = tid & 1;
    const float* src = in + ((size_t)b * C + c) * N + i0 + ih * 16;
    const float av = a_s[c], dv = d_s[c];
    #pragma unroll
    for (int k4 = 0; k4 < 4; ++k4) {
      float4 v = *(const float4*)(src + k4 * 4);
      const int i = ih * 16 + k4 * 4;
      xt[(i + 0) * 136 + c] = f2bf(fmaf(v.x, av, dv));
      xt[(i + 1) * 136 + c] = f2bf(fmaf(v.y, av, dv));
      xt[(i + 2) * 136 + c] = f2bf(fmaf(v.z, av, dv));
      xt[(i + 3) * 136 + c] = f2bf(fmaf(v.w, av, dv));
    }
  }
  __syncthreads();

  const int w = tid >> 6, lane = tid & 63, quad = lane >> 4, l15 = lane & 15;
  const ushort* wmats[2];
  wmats[0] = z ? wkb : wqb;
  wmats[1] = wvb;

  bf16x8 aw[2][2][4];
  for (int m = 0; m < nm; ++m)
    #pragma unroll
    for (int mt2 = 0; mt2 < 2; ++mt2)
      #pragma unroll
      for (int ks = 0; ks < 4; ++ks)
        aw[m][mt2][ks] = *(const bf16x8*)(wmats[m] + (size_t)(w * 32 + mt2 * 16 + l15) * 128 + ks * 32 + quad * 8);

  f32x4 acc[2][2][2];
  for (int m = 0; m < nm; ++m)
    #pragma unroll
    for (int mt2 = 0; mt2 < 2; ++mt2)
      #pragma unroll
      for (int nt = 0; nt < 2; ++nt) acc[m][mt2][nt] = (f32x4){0.f, 0.f, 0.f, 0.f};

  #pragma unroll
  for (int nt = 0; nt < 2; ++nt) {
    bf16x8 bo[4];
    #pragma unroll
    for (int ks = 0; ks < 4; ++ks)
      bo[ks] = *(const bf16x8*)(&xt[(nt * 16 + l15) * 136 + ks * 32 + quad * 8]);
    for (int m = 0; m < nm; ++m)
      #pragma unroll
      for (int mt2 = 0; mt2 < 2; ++mt2)
        #pragma unroll
        for (int ks = 0; ks < 4; ++ks)
          acc[m][mt2][nt] = __builtin_amdgcn_mfma_f32_16x16x32_bf16(aw[m][mt2][ks], bo[ks], acc[m][mt2][nt], 0, 0, 0);
  }

  for (int m = 0; m < nm; ++m) {
    const float* bias = z ? (m == 0 ? bk : bv) : bq;
    #pragma unroll
    for (int mt2 = 0; mt2 < 2; ++mt2) {
      const int ob = w * 32 + mt2 * 16 + quad * 4;
      float4 bb4 = *(const float4*)(bias + ob);
      float bbv[4] = {bb4.x, bb4.y, bb4.z, bb4.w};
      #pragma unroll
      for (int nt = 0; nt < 2; ++nt) {
        const int i = i0 + nt * 16 + l15;
        if (m == 0) {  // q or k: [i][c] layout
          ushort* dst = z ? kt : qt;
          ushort h[4];
          #pragma unroll
          for (int r = 0; r < 4; ++r) h[r] = f2bf(acc[m][mt2][nt][r] + bbv[r]);
          *(uint2*)(dst + ((size_t)b * N + i) * C + ob) = *(uint2*)h;
        } else {       // v: [c][i] layout
          #pragma unroll
          for (int r = 0; r < 4; ++r)
            vb[((size_t)b * C + ob + r) * N + i] = f2bf(acc[m][mt2][nt][r] + bbv[r]);
        }
      }
    }
  }
}

// ---------------------------------------------------------------------------
// Kernel 3: MFMA flash attention (round-7 structure): TQ=64, no-max softmax,
// K-split, register prefetch, single-buffered. grid=(64 q-tiles, P, 2).
// Emits unnormalized partial O (bf16) + per-row l.
// ---------------------------------------------------------------------------
__global__ __launch_bounds__(256) void attn_kernel(
    const ushort* __restrict__ qt, const ushort* __restrict__ kt,
    const ushort* __restrict__ vb, float* __restrict__ pml,
    ushort* __restrict__ pO, int part_keys) {
  __shared__ __align__(16) ushort ksts[32 * 136];   // K^T [j][c]
  __shared__ __align__(16) ushort vss [128 * 40];   // V   [c][j]
  __shared__ __align__(16) ushort pss [4][16 * 40]; // per-wave P

  const int b    = blockIdx.z;
  const int part = blockIdx.y;
  const int i0   = blockIdx.x * 64;
  const int tid  = threadIdx.x;
  const int w    = tid >> 6;
  const int lane = tid & 63;
  const int quad = lane >> 4;
  const int l15  = lane & 15;
  const float scale = 0.08838834764831845f;

  bf16x8 aq[4];
  {
    const ushort* qrow = qt + ((size_t)b * N + i0 + w * 16 + l15) * C;
    #pragma unroll
    for (int ks = 0; ks < 4; ++ks)
      aq[ks] = *(const bf16x8*)(qrow + ks * 32 + quad * 8);
  }

  float lacc[4] = {0.f, 0.f, 0.f, 0.f};
  f32x4 Ofr[8];
  #pragma unroll
  for (int mt = 0; mt < 8; ++mt) Ofr[mt] = (f32x4){0.f, 0.f, 0.f, 0.f};

  const int krow = tid >> 3, kseg = tid & 7;
  const int vc = tid >> 1, vseg = tid & 1;
  const ushort* kbase = kt + ((size_t)b * N + krow) * C + kseg * 16;
  const ushort* vbase = vb + ((size_t)b * C + vc) * N + vseg * 16;
  uint4* dk = (uint4*)(&ksts[krow * 136 + kseg * 16]);
  uint4* dv = (uint4*)(&vss[vc * 40 + vseg * 16]);

  const int tcount = part_keys >> 5;
  const int jbase = part * part_keys;
  // prefetch chunk 0
  uint4 k0, k1, v0, v1;
  {
    const uint4* sk = (const uint4*)(kbase + (size_t)jbase * C);
    k0 = sk[0]; k1 = sk[1];
    const uint4* sv = (const uint4*)(vbase + jbase);
    v0 = sv[0]; v1 = sv[1];
  }

  for (int t = 0; t < tcount; ++t) {
    __syncthreads();  // prev chunk's LDS fully consumed
    dk[0] = k0; dk[1] = k1;   // waits vmcnt for the prefetched loads
    dv[0] = v0; dv[1] = v1;
    __syncthreads();  // staging visible
    if (t + 1 < tcount) {     // issue next chunk's loads; overlap with compute
      const int j1 = jbase + (t + 1) * 32;
      const uint4* sk = (const uint4*)(kbase + (size_t)j1 * C);
      k0 = sk[0]; k1 = sk[1];
      const uint4* sv = (const uint4*)(vbase + j1);
      v0 = sv[0]; v1 = sv[1];
    }

    // S = Q K^T : wave's 16 rows x 32 keys
    f32x4 sfr[2];
    #pragma unroll
    for (int nt = 0; nt < 2; ++nt) {
      f32x4 s = (f32x4){0.f, 0.f, 0.f, 0.f};
      #pragma unroll
      for (int ks = 0; ks < 4; ++ks) {
        bf16x8 bk = *(const bf16x8*)(&ksts[(nt * 16 + l15) * 136 + ks * 32 + quad * 8]);
        s = __builtin_amdgcn_mfma_f32_16x16x32_bf16(aq[ks], bk, s, 0, 0, 0);
      }
      sfr[nt] = s;
    }

    // no-max softmax: p = exp(s*scale); defer l reduction to after the loop
    #pragma unroll
    for (int r = 0; r < 4; ++r) {
      float p0 = __expf(sfr[0][r] * scale);
      float p1 = __expf(sfr[1][r] * scale);
      pss[w][(quad * 4 + r) * 40 + l15]      = f2bf(p0);
      pss[w][(quad * 4 + r) * 40 + 16 + l15] = f2bf(p1);
      lacc[r] += p0 + p1;
    }
    // PV: A = V[c][j], B = P^T[j][i]
    bf16x8 bpf = *(const bf16x8*)(&pss[w][l15 * 40 + quad * 8]);
    #pragma unroll
    for (int mt = 0; mt < 8; ++mt) {
      bf16x8 av = *(const bf16x8*)(&vss[(mt * 16 + l15) * 40 + quad * 8]);
      Ofr[mt] = __builtin_amdgcn_mfma_f32_16x16x32_bf16(av, bpf, Ofr[mt], 0, 0, 0);
    }
  }

  // one-time l reduction across the 16 columns
  #pragma unroll
  for (int off = 1; off < 16; off <<= 1)
    #pragma unroll
    for (int r = 0; r < 4; ++r)
      lacc[r] += __shfl_xor(lacc[r], off, 64);

  const size_t blk = ((size_t)part * 64 + blockIdx.x) * 2 + b;
  if (l15 == 0) {
    float* lb = pml + blk * 64;
    #pragma unroll
    for (int r = 0; r < 4; ++r)
      lb[w * 16 + quad * 4 + r] = lacc[r];
  }
  ushort* ob = pO + blk * 8192;
  const int irow = w * 16 + l15;
  #pragma unroll
  for (int mt = 0; mt < 8; ++mt) {
    ushort h[4];
    #pragma unroll
    for (int r = 0; r < 4; ++r) h[r] = f2bf(Ofr[mt][r]);
    *(uint2*)(ob + irow * 128 + mt * 16 + quad * 4) = *(uint2*)h;
  }
}

// ---------------------------------------------------------------------------
// Kernel 4: sum partials + normalize + proj + bias + residual.
// grid=(128 tiles32, 2), 256 thr.
// ---------------------------------------------------------------------------
__global__ __launch_bounds__(256) void combine_kernel(
    const float* __restrict__ x, const float* __restrict__ bp,
    const ushort* __restrict__ wpb, const float* __restrict__ pml,
    const ushort* __restrict__ pO, float* __restrict__ out, int nparts) {
  __shared__ __align__(16) ushort obf[32 * 136];
  __shared__ float linv_s[32];
  const int qt32 = blockIdx.x, b = blockIdx.y;
  const int qt64 = qt32 >> 1, rowoff = (qt32 & 1) * 32;
  const int tid = threadIdx.x;

  if (tid < 32) {
    const int row = rowoff + tid;
    float sum = 0.f;
    for (int p = 0; p < nparts; ++p) {
      const size_t blk = ((size_t)p * 64 + qt64) * 2 + b;
      sum += pml[blk * 64 + row];
    }
    linv_s[tid] = 1.f / sum;
  }
  __syncthreads();

  const int lrow = tid >> 3, seg = tid & 7;   // 32 rows x 8 segs of 16
  const int prow = rowoff + lrow;
  float acc[16];
  #pragma unroll
  for (int j = 0; j < 16; ++j) acc[j] = 0.f;
  for (int p = 0; p < nparts; ++p) {
    const size_t blk = ((size_t)p * 64 + qt64) * 2 + b;
    const ushort* src = pO + blk * 8192 + prow * 128 + seg * 16;
    uint4 u[2];
    u[0] = *(const uint4*)src;
    u[1] = *(const uint4*)(src + 8);
    const ushort* hs = (const ushort*)u;
    #pragma unroll
    for (int j = 0; j < 16; ++j)
      acc[j] += __uint_as_float(((unsigned)hs[j]) << 16);
  }
  {
    const float linv = linv_s[lrow];
    ushort h[16];
    #pragma unroll
    for (int j = 0; j < 16; ++j) h[j] = f2bf(acc[j] * linv);
    uint4* d = (uint4*)(&obf[lrow * 136 + seg * 16]);
    d[0] = ((uint4*)h)[0];
    d[1] = ((uint4*)h)[1];
  }
  __syncthreads();

  // proj epilogue (verified pattern)
  const int w = tid >> 6, lane = tid & 63, quad = lane >> 4, l15 = lane & 15;
  const int i0 = qt32 * 32;
  bf16x8 awp[2][4];
  #pragma unroll
  for (int mt2 = 0; mt2 < 2; ++mt2)
    #pragma unroll
    for (int ks = 0; ks < 4; ++ks)
      awp[mt2][ks] = *(const bf16x8*)(wpb + (size_t)(w * 32 + mt2 * 16 + l15) * 128 + ks * 32 + quad * 8);

  #pragma unroll
  for (int nt = 0; nt < 2; ++nt) {
    bf16x8 bo[4];
    #pragma unroll
    for (int ks = 0; ks < 4; ++ks)
      bo[ks] = *(const bf16x8*)(&obf[(nt * 16 + l15) * 136 + ks * 32 + quad * 8]);
    #pragma unroll
    for (int mt2 = 0; mt2 < 2; ++mt2) {
      f32x4 acc2 = (f32x4){0.f, 0.f, 0.f, 0.f};
      #pragma unroll
      for (int ks = 0; ks < 4; ++ks)
        acc2 = __builtin_amdgcn_mfma_f32_16x16x32_bf16(awp[mt2][ks], bo[ks], acc2, 0, 0, 0);
      #pragma unroll
      for (int r = 0; r < 4; ++r) {
        const int o = w * 32 + mt2 * 16 + quad * 4 + r;
        const int i = i0 + nt * 16 + l15;
        const size_t off = ((size_t)b * C + o) * (size_t)N + i;
        out[off] = x[off] + acc2[r] + bp[o];
      }
    }
  }
}

// ---------------------------------------------------------------------------
extern "C" void kernel_launch(void* const* d_in, const int* in_sizes, int n_in,
                              void* d_out, int out_size, void* d_ws, size_t ws_size,
                              hipStream_t stream) {
  const float* x  = (const float*)d_in[0];
  const float* cc = (const float*)d_in[1];
  const float* g1 = (const float*)d_in[2];
  const float* b1 = (const float*)d_in[3];
  const float* g2 = (const float*)d_in[4];
  const float* b2 = (const float*)d_in[5];
  const float* wq = (const float*)d_in[6];
  const float* bq = (const float*)d_in[7];
  const float* wk = (const float*)d_in[8];
  const float* bk = (const float*)d_in[9];
  const float* wv = (const float*)d_in[10];
  const float* bv = (const float*)d_in[11];
  const float* wp = (const float*)d_in[12];
  const float* bp = (const float*)d_in[13];
  float* out = (float*)d_out;

  const size_t BNC = (size_t)B * N * C;          // 1,048,576
  char* base = (char*)d_ws;
  float* stats = (float*)base;                    // 16 x 8 x 2 floats
  ushort* qt = (ushort*)(base + 4096);
  ushort* kt = qt + BNC;
  ushort* vb = kt + BNC;
  ushort* wb = vb + BNC;                          // 4 x 16384 bf16
  ushort* wqb = wb, *wkb = wb + 16384, *wvb = wb + 32768, *wpb = wb + 49152;
  float* pml = (float*)(wb + 65536);

  const size_t fixed = 4096 + 3 * BNC * 2 + 131072;           // 6,426,624
  const size_t per_part = 32768 + (size_t)64 * 2 * 8192 * 2;  // 2,129,920
  const int nparts = (ws_size >= fixed + 8 * per_part) ? 8
                   : (ws_size >= fixed + 4 * per_part) ? 4 : 2;
  ushort* pO = (ushort*)((char*)pml + (size_t)nparts * 32768);
  const int part_keys = N / nparts;

  gn_partial_kernel<<<dim3(64, 3), 256, 0, stream>>>(x, cc, wq, wk, wv, wp, stats, wb);
  qkv_kernel<<<dim3(128, 2, 2), 256, 0, stream>>>(x, cc, g1, b1, g2, b2,
                                                  wqb, wkb, wvb, bq, bk, bv, stats,
                                                  qt, kt, vb);
  attn_kernel<<<dim3(64, nparts, 2), 256, 0, stream>>>(qt, kt, vb, pml, pO, part_keys);
  combine_kernel<<<dim3(128, 2), 256, 0, stream>>>(x, bp, wpb, pml, pO, out, nparts);
}

// Round 10
// 136.750 us; speedup vs baseline: 1.1088x; 1.1088x over previous
//
#include <hip/hip_runtime.h>
#include <math.h>

#define C 128
#define N 4096
#define B 2
#define CPG 32

typedef __attribute__((ext_vector_type(8))) short bf16x8;
typedef __attribute__((ext_vector_type(4))) float f32x4;

static __device__ __forceinline__ ushort f2bf(float f) {
  unsigned u = __float_as_uint(f);
  unsigned r = (u + 0x7fffu + ((u >> 16) & 1u)) >> 16;  // RNE
  return (ushort)r;
}

// ---------------------------------------------------------------------------
// Kernel 1: GroupNorm per-slice sums (y=0,1) + weight fp32->bf16 (y=2, x<32).
// stats[t][bg][slice][2] — each slot written by exactly one block: no atomics,
// no memset dispatch. qkv sums the 8 slices.
// ---------------------------------------------------------------------------
__global__ __launch_bounds__(256) void gn_partial_kernel(
    const float* __restrict__ x, const float* __restrict__ cc,
    const float* __restrict__ wq, const float* __restrict__ wk,
    const float* __restrict__ wv, const float* __restrict__ wp,
    float* __restrict__ stats, ushort* __restrict__ wb) {
  if (blockIdx.y == 2) {
    if (blockIdx.x >= 32) return;
    int idx = (blockIdx.x * 256 + threadIdx.x) * 8;   // [0, 65536)
    const float* srcs[4] = {wq, wk, wv, wp};
    const float* s = srcs[idx >> 14] + (idx & 16383);
    float4 a = *(const float4*)s;
    float4 b2 = *(const float4*)(s + 4);
    ushort h[8];
    h[0] = f2bf(a.x);  h[1] = f2bf(a.y);  h[2] = f2bf(a.z);  h[3] = f2bf(a.w);
    h[4] = f2bf(b2.x); h[5] = f2bf(b2.y); h[6] = f2bf(b2.z); h[7] = f2bf(b2.w);
    *(uint4*)(wb + idx) = *(uint4*)h;
    return;
  }
  const int t = blockIdx.y;
  const int bg = blockIdx.x >> 3, slice = blockIdx.x & 7;
  const float* in = (t == 0) ? x : cc;
  const float4* base = (const float4*)(in + (size_t)bg * CPG * N + slice * 16384);
  float s = 0.f, sq = 0.f;
  #pragma unroll
  for (int k = 0; k < 16; ++k) {
    float4 v = base[threadIdx.x + k * 256];
    s  += v.x + v.y + v.z + v.w;
    sq += v.x * v.x + v.y * v.y + v.z * v.z + v.w * v.w;
  }
  #pragma unroll
  for (int off = 32; off > 0; off >>= 1) {
    s  += __shfl_down(s, off, 64);
    sq += __shfl_down(sq, off, 64);
  }
  __shared__ float ss[4], ssq[4];
  const int wid = threadIdx.x >> 6;
  if ((threadIdx.x & 63) == 0) { ss[wid] = s; ssq[wid] = sq; }
  __syncthreads();
  if (threadIdx.x == 0) {
    stats[((t * 8 + bg) * 8 + slice) * 2 + 0] = ss[0] + ss[1] + ss[2] + ss[3];
    stats[((t * 8 + bg) * 8 + slice) * 2 + 1] = ssq[0] + ssq[1] + ssq[2] + ssq[3];
  }
}

// ---------------------------------------------------------------------------
// Kernel 2 (r7 structure): MFMA qkv. grid=(128 i-tiles of 32, 6=which*2+b),
// 256 thr — 768 UNIFORM blocks (3/CU). Uniform work beats merged double-duty
// blocks (r8/r9 regression: merged grid = 256 heavy blocks = 1/CU critical path).
// ---------------------------------------------------------------------------
__global__ __launch_bounds__(256) void qkv_kernel(
    const float* __restrict__ x, const float* __restrict__ cc,
    const float* __restrict__ g1, const float* __restrict__ b1,
    const float* __restrict__ g2, const float* __restrict__ b2,
    const ushort* __restrict__ wqb, const ushort* __restrict__ wkb,
    const ushort* __restrict__ wvb,
    const float* __restrict__ bq, const float* __restrict__ bk,
    const float* __restrict__ bv, const float* __restrict__ stats,
    ushort* __restrict__ qt, ushort* __restrict__ kt, ushort* __restrict__ vb) {
  const int zw    = blockIdx.y;
  const int which = zw >> 1;
  const int b     = zw & 1;
  const int i0    = blockIdx.x * 32;
  const int tid   = threadIdx.x;

  const float *in, *bias, *gamma, *beta;
  const ushort* wmat;
  int tensor;
  if (which == 0)      { in = cc; wmat = wqb; bias = bq; gamma = g2; beta = b2; tensor = 1; }
  else if (which == 1) { in = x;  wmat = wkb; bias = bk; gamma = g1; beta = b1; tensor = 0; }
  else                 { in = x;  wmat = wvb; bias = bv; gamma = g1; beta = b1; tensor = 0; }

  __shared__ float a_s[C], d_s[C];
  __shared__ __align__(16) ushort xt[32 * 136];  // Xn^T [i][c]
  if (tid < C) {
    const int ch = tid, g = ch >> 5;
    const float cnt = (float)(CPG * N);
    float S = 0.f, SQ = 0.f;
    #pragma unroll
    for (int sl = 0; sl < 8; ++sl) {
      S  += stats[((tensor * 8 + b * 4 + g) * 8 + sl) * 2 + 0];
      SQ += stats[((tensor * 8 + b * 4 + g) * 8 + sl) * 2 + 1];
    }
    float mean = S / cnt;
    float var  = SQ / cnt - mean * mean;
    float rstd = rsqrtf(var + 1e-6f);
    float ga = gamma[ch];
    a_s[ch] = rstd * ga;
    d_s[ch] = beta[ch] - mean * rstd * ga;
  }
  __syncthreads();

  {  // stage + normalize + transpose: thread covers (c = tid>>1, 16 i's)
    const int c = tid >> 1, ih = tid & 1;
    const float* src = in + ((size_t)b * C + c) * N + i0 + ih * 16;
    const float av = a_s[c], dv = d_s[c];
    #pragma unroll
    for (int k4 = 0; k4 < 4; ++k4) {
      float4 v = *(const float4*)(src + k4 * 4);
      const int i = ih * 16 + k4 * 4;
      xt[(i + 0) * 136 + c] = f2bf(fmaf(v.x, av, dv));
      xt[(i + 1) * 136 + c] = f2bf(fmaf(v.y, av, dv));
      xt[(i + 2) * 136 + c] = f2bf(fmaf(v.z, av, dv));
      xt[(i + 3) * 136 + c] = f2bf(fmaf(v.w, av, dv));
    }
  }
  __syncthreads();

  const int w = tid >> 6, lane = tid & 63, quad = lane >> 4, l15 = lane & 15;
  bf16x8 aw[2][4];
  #pragma unroll
  for (int mt2 = 0; mt2 < 2; ++mt2)
    #pragma unroll
    for (int ks = 0; ks < 4; ++ks)
      aw[mt2][ks] = *(const bf16x8*)(wmat + (size_t)(w * 32 + mt2 * 16 + l15) * 128 + ks * 32 + quad * 8);

  f32x4 acc[2][2];
  #pragma unroll
  for (int mt2 = 0; mt2 < 2; ++mt2)
    #pragma unroll
    for (int nt = 0; nt < 2; ++nt) acc[mt2][nt] = (f32x4){0.f, 0.f, 0.f, 0.f};

  #pragma unroll
  for (int nt = 0; nt < 2; ++nt) {
    bf16x8 bo[4];
    #pragma unroll
    for (int ks = 0; ks < 4; ++ks)
      bo[ks] = *(const bf16x8*)(&xt[(nt * 16 + l15) * 136 + ks * 32 + quad * 8]);
    #pragma unroll
    for (int mt2 = 0; mt2 < 2; ++mt2)
      #pragma unroll
      for (int ks = 0; ks < 4; ++ks)
        acc[mt2][nt] = __builtin_amdgcn_mfma_f32_16x16x32_bf16(aw[mt2][ks], bo[ks], acc[mt2][nt], 0, 0, 0);
  }

  #pragma unroll
  for (int mt2 = 0; mt2 < 2; ++mt2) {
    const int ob = w * 32 + mt2 * 16 + quad * 4;
    float4 bb4 = *(const float4*)(bias + ob);
    float bbv[4] = {bb4.x, bb4.y, bb4.z, bb4.w};
    #pragma unroll
    for (int nt = 0; nt < 2; ++nt) {
      const int i = i0 + nt * 16 + l15;
      if (which <= 1) {
        ushort* dst = (which == 0 ? qt : kt);
        ushort h[4];
        #pragma unroll
        for (int r = 0; r < 4; ++r) h[r] = f2bf(acc[mt2][nt][r] + bbv[r]);
        *(uint2*)(dst + ((size_t)b * N + i) * C + ob) = *(uint2*)h;
      } else {
        #pragma unroll
        for (int r = 0; r < 4; ++r)
          vb[((size_t)b * C + ob + r) * N + i] = f2bf(acc[mt2][nt][r] + bbv[r]);
      }
    }
  }
}

// ---------------------------------------------------------------------------
// Kernel 3 (r7 structure, best measured): MFMA flash attention, TQ=64,
// no-max softmax, K-split, register prefetch. grid=(64 q-tiles, P, 2).
// ---------------------------------------------------------------------------
__global__ __launch_bounds__(256) void attn_kernel(
    const ushort* __restrict__ qt, const ushort* __restrict__ kt,
    const ushort* __restrict__ vb, float* __restrict__ pml,
    ushort* __restrict__ pO, int part_keys) {
  __shared__ __align__(16) ushort ksts[32 * 136];   // K^T [j][c]
  __shared__ __align__(16) ushort vss [128 * 40];   // V   [c][j]
  __shared__ __align__(16) ushort pss [4][16 * 40]; // per-wave P

  const int b    = blockIdx.z;
  const int part = blockIdx.y;
  const int i0   = blockIdx.x * 64;
  const int tid  = threadIdx.x;
  const int w    = tid >> 6;
  const int lane = tid & 63;
  const int quad = lane >> 4;
  const int l15  = lane & 15;
  const float scale = 0.08838834764831845f;

  bf16x8 aq[4];
  {
    const ushort* qrow = qt + ((size_t)b * N + i0 + w * 16 + l15) * C;
    #pragma unroll
    for (int ks = 0; ks < 4; ++ks)
      aq[ks] = *(const bf16x8*)(qrow + ks * 32 + quad * 8);
  }

  float lacc[4] = {0.f, 0.f, 0.f, 0.f};
  f32x4 Ofr[8];
  #pragma unroll
  for (int mt = 0; mt < 8; ++mt) Ofr[mt] = (f32x4){0.f, 0.f, 0.f, 0.f};

  const int krow = tid >> 3, kseg = tid & 7;
  const int vc = tid >> 1, vseg = tid & 1;
  const ushort* kbase = kt + ((size_t)b * N + krow) * C + kseg * 16;
  const ushort* vbase = vb + ((size_t)b * C + vc) * N + vseg * 16;
  uint4* dk = (uint4*)(&ksts[krow * 136 + kseg * 16]);
  uint4* dv = (uint4*)(&vss[vc * 40 + vseg * 16]);

  const int tcount = part_keys >> 5;
  const int jbase = part * part_keys;
  // prefetch chunk 0
  uint4 k0, k1, v0, v1;
  {
    const uint4* sk = (const uint4*)(kbase + (size_t)jbase * C);
    k0 = sk[0]; k1 = sk[1];
    const uint4* sv = (const uint4*)(vbase + jbase);
    v0 = sv[0]; v1 = sv[1];
  }

  for (int t = 0; t < tcount; ++t) {
    __syncthreads();  // prev chunk's LDS fully consumed
    dk[0] = k0; dk[1] = k1;   // waits vmcnt for the prefetched loads
    dv[0] = v0; dv[1] = v1;
    __syncthreads();  // staging visible
    if (t + 1 < tcount) {     // issue next chunk's loads; overlap with compute
      const int j1 = jbase + (t + 1) * 32;
      const uint4* sk = (const uint4*)(kbase + (size_t)j1 * C);
      k0 = sk[0]; k1 = sk[1];
      const uint4* sv = (const uint4*)(vbase + j1);
      v0 = sv[0]; v1 = sv[1];
    }

    // S = Q K^T : wave's 16 rows x 32 keys
    f32x4 sfr[2];
    #pragma unroll
    for (int nt = 0; nt < 2; ++nt) {
      f32x4 s = (f32x4){0.f, 0.f, 0.f, 0.f};
      #pragma unroll
      for (int ks = 0; ks < 4; ++ks) {
        bf16x8 bk = *(const bf16x8*)(&ksts[(nt * 16 + l15) * 136 + ks * 32 + quad * 8]);
        s = __builtin_amdgcn_mfma_f32_16x16x32_bf16(aq[ks], bk, s, 0, 0, 0);
      }
      sfr[nt] = s;
    }

    // no-max softmax: p = exp(s*scale); defer l reduction to after the loop
    #pragma unroll
    for (int r = 0; r < 4; ++r) {
      float p0 = __expf(sfr[0][r] * scale);
      float p1 = __expf(sfr[1][r] * scale);
      pss[w][(quad * 4 + r) * 40 + l15]      = f2bf(p0);
      pss[w][(quad * 4 + r) * 40 + 16 + l15] = f2bf(p1);
      lacc[r] += p0 + p1;
    }
    // PV: A = V[c][j], B = P^T[j][i]
    bf16x8 bpf = *(const bf16x8*)(&pss[w][l15 * 40 + quad * 8]);
    #pragma unroll
    for (int mt = 0; mt < 8; ++mt) {
      bf16x8 av = *(const bf16x8*)(&vss[(mt * 16 + l15) * 40 + quad * 8]);
      Ofr[mt] = __builtin_amdgcn_mfma_f32_16x16x32_bf16(av, bpf, Ofr[mt], 0, 0, 0);
    }
  }

  // one-time l reduction across the 16 columns
  #pragma unroll
  for (int off = 1; off < 16; off <<= 1)
    #pragma unroll
    for (int r = 0; r < 4; ++r)
      lacc[r] += __shfl_xor(lacc[r], off, 64);

  const size_t blk = ((size_t)part * 64 + blockIdx.x) * 2 + b;
  if (l15 == 0) {
    float* lb = pml + blk * 64;
    #pragma unroll
    for (int r = 0; r < 4; ++r)
      lb[w * 16 + quad * 4 + r] = lacc[r];
  }
  ushort* ob = pO + blk * 8192;
  const int irow = w * 16 + l15;
  #pragma unroll
  for (int mt = 0; mt < 8; ++mt) {
    ushort h[4];
    #pragma unroll
    for (int r = 0; r < 4; ++r) h[r] = f2bf(Ofr[mt][r]);
    *(uint2*)(ob + irow * 128 + mt * 16 + quad * 4) = *(uint2*)h;
  }
}

// ---------------------------------------------------------------------------
// Kernel 4 (r7 structure): sum partials + normalize + proj + bias + residual.
// grid=(128 tiles32, 2), 256 thr.
// ---------------------------------------------------------------------------
__global__ __launch_bounds__(256) void combine_kernel(
    const float* __restrict__ x, const float* __restrict__ bp,
    const ushort* __restrict__ wpb, const float* __restrict__ pml,
    const ushort* __restrict__ pO, float* __restrict__ out, int nparts) {
  __shared__ __align__(16) ushort obf[32 * 136];
  __shared__ float linv_s[32];
  const int qt32 = blockIdx.x, b = blockIdx.y;
  const int qt64 = qt32 >> 1, rowoff = (qt32 & 1) * 32;
  const int tid = threadIdx.x;

  if (tid < 32) {
    const int row = rowoff + tid;
    float sum = 0.f;
    for (int p = 0; p < nparts; ++p) {
      const size_t blk = ((size_t)p * 64 + qt64) * 2 + b;
      sum += pml[blk * 64 + row];
    }
    linv_s[tid] = 1.f / sum;
  }
  __syncthreads();

  const int lrow = tid >> 3, seg = tid & 7;   // 32 rows x 8 segs of 16
  const int prow = rowoff + lrow;
  float acc[16];
  #pragma unroll
  for (int j = 0; j < 16; ++j) acc[j] = 0.f;
  for (int p = 0; p < nparts; ++p) {
    const size_t blk = ((size_t)p * 64 + qt64) * 2 + b;
    const ushort* src = pO + blk * 8192 + prow * 128 + seg * 16;
    uint4 u[2];
    u[0] = *(const uint4*)src;
    u[1] = *(const uint4*)(src + 8);
    const ushort* hs = (const ushort*)u;
    #pragma unroll
    for (int j = 0; j < 16; ++j)
      acc[j] += __uint_as_float(((unsigned)hs[j]) << 16);
  }
  {
    const float linv = linv_s[lrow];
    ushort h[16];
    #pragma unroll
    for (int j = 0; j < 16; ++j) h[j] = f2bf(acc[j] * linv);
    uint4* d = (uint4*)(&obf[lrow * 136 + seg * 16]);
    d[0] = ((uint4*)h)[0];
    d[1] = ((uint4*)h)[1];
  }
  __syncthreads();

  // proj epilogue (verified pattern)
  const int w = tid >> 6, lane = tid & 63, quad = lane >> 4, l15 = lane & 15;
  const int i0 = qt32 * 32;
  bf16x8 awp[2][4];
  #pragma unroll
  for (int mt2 = 0; mt2 < 2; ++mt2)
    #pragma unroll
    for (int ks = 0; ks < 4; ++ks)
      awp[mt2][ks] = *(const bf16x8*)(wpb + (size_t)(w * 32 + mt2 * 16 + l15) * 128 + ks * 32 + quad * 8);

  #pragma unroll
  for (int nt = 0; nt < 2; ++nt) {
    bf16x8 bo[4];
    #pragma unroll
    for (int ks = 0; ks < 4; ++ks)
      bo[ks] = *(const bf16x8*)(&obf[(nt * 16 + l15) * 136 + ks * 32 + quad * 8]);
    #pragma unroll
    for (int mt2 = 0; mt2 < 2; ++mt2) {
      f32x4 acc2 = (f32x4){0.f, 0.f, 0.f, 0.f};
      #pragma unroll
      for (int ks = 0; ks < 4; ++ks)
        acc2 = __builtin_amdgcn_mfma_f32_16x16x32_bf16(awp[mt2][ks], bo[ks], acc2, 0, 0, 0);
      #pragma unroll
      for (int r = 0; r < 4; ++r) {
        const int o = w * 32 + mt2 * 16 + quad * 4 + r;
        const int i = i0 + nt * 16 + l15;
        const size_t off = ((size_t)b * C + o) * (size_t)N + i;
        out[off] = x[off] + acc2[r] + bp[o];
      }
    }
  }
}

// ---------------------------------------------------------------------------
extern "C" void kernel_launch(void* const* d_in, const int* in_sizes, int n_in,
                              void* d_out, int out_size, void* d_ws, size_t ws_size,
                              hipStream_t stream) {
  const float* x  = (const float*)d_in[0];
  const float* cc = (const float*)d_in[1];
  const float* g1 = (const float*)d_in[2];
  const float* b1 = (const float*)d_in[3];
  const float* g2 = (const float*)d_in[4];
  const float* b2 = (const float*)d_in[5];
  const float* wq = (const float*)d_in[6];
  const float* bq = (const float*)d_in[7];
  const float* wk = (const float*)d_in[8];
  const float* bk = (const float*)d_in[9];
  const float* wv = (const float*)d_in[10];
  const float* bv = (const float*)d_in[11];
  const float* wp = (const float*)d_in[12];
  const float* bp = (const float*)d_in[13];
  float* out = (float*)d_out;

  const size_t BNC = (size_t)B * N * C;          // 1,048,576
  char* base = (char*)d_ws;
  float* stats = (float*)base;                    // 16 x 8 x 2 floats
  ushort* qt = (ushort*)(base + 4096);
  ushort* kt = qt + BNC;
  ushort* vb = kt + BNC;
  ushort* wb = vb + BNC;                          // 4 x 16384 bf16
  ushort* wqb = wb, *wkb = wb + 16384, *wvb = wb + 32768, *wpb = wb + 49152;
  float* pml = (float*)(wb + 65536);

  const size_t fixed = 4096 + 3 * BNC * 2 + 131072;           // 6,426,624
  const size_t per_part = 32768 + (size_t)64 * 2 * 8192 * 2;  // 2,129,920
  const int nparts = (ws_size >= fixed + 8 * per_part) ? 8
                   : (ws_size >= fixed + 4 * per_part) ? 4 : 2;
  ushort* pO = (ushort*)((char*)pml + (size_t)nparts * 32768);
  const int part_keys = N / nparts;

  gn_partial_kernel<<<dim3(64, 3), 256, 0, stream>>>(x, cc, wq, wk, wv, wp, stats, wb);
  qkv_kernel<<<dim3(128, 6), 256, 0, stream>>>(x, cc, g1, b1, g2, b2,
                                               wqb, wkb, wvb, bq, bk, bv, stats,
                                               qt, kt, vb);
  attn_kernel<<<dim3(64, nparts, 2), 256, 0, stream>>>(qt, kt, vb, pml, pO, part_keys);
  combine_kernel<<<dim3(128, 2), 256, 0, stream>>>(x, bp, wpb, pml, pO, out, nparts);
}